// Round 5
// baseline (205.733 us; speedup 1.0000x reference)
//
#include <hip/hip_runtime.h>

typedef __attribute__((ext_vector_type(8))) short short8;
typedef __attribute__((ext_vector_type(4))) float f32x4;

#define N_ATOMS 4096
#define N_NEIGH 32
#define IN_F 128
#define HID 256
#define OUT_F 128
#define N_SPECIES 64
#define GRP 8
#define MAX_GROUPS 576  // sum ceil(c_s/8) <= 512 + 56; padded to 8*72 for swizzle

// Truncation-based hi/lo split: hi = top 16 bits (exact chop), lo = (v - hi)
// truncated to bf16. v - hi is exact in fp32, total rep error <= 2^-16 |v|.
struct HL { short h, l; };
__device__ __forceinline__ HL split2(float v) {
  unsigned u = __float_as_uint(v);
  float lo = v - __uint_as_float(u & 0xFFFF0000u);
  HL o;
  o.h = (short)(u >> 16);
  o.l = (short)(__float_as_uint(lo) >> 16);
  return o;
}

// ---------- kernel 1: (block 0) counting sort | (blocks 1..) W split ----------
__global__ __launch_bounds__(256) void prep_kernel(
    const float* __restrict__ W1, const float* __restrict__ W2,
    const int* __restrict__ sp_idx,
    unsigned short* __restrict__ w1h, unsigned short* __restrict__ w1l,
    unsigned short* __restrict__ w2h, unsigned short* __restrict__ w2l,
    int* __restrict__ atom_order, int* __restrict__ grp_sp,
    int* __restrict__ grp_base, int* __restrict__ grp_cnt,
    int* __restrict__ n_groups) {
  const int t = threadIdx.x;
  if (blockIdx.x == 0) {
    __shared__ int cnt[N_SPECIES], off[N_SPECIES], cur[N_SPECIES], gb[N_SPECIES];
    if (t < N_SPECIES) cnt[t] = 0;
    __syncthreads();
    for (int a = t; a < N_ATOMS; a += 256) atomicAdd(&cnt[sp_idx[a]], 1);
    __syncthreads();
    if (t == 0) {
      int o = 0, g = 0;
      for (int s = 0; s < N_SPECIES; ++s) {
        off[s] = o; cur[s] = o; gb[s] = g;
        o += cnt[s];
        g += (cnt[s] + GRP - 1) / GRP;
      }
      *n_groups = g;
    }
    __syncthreads();
    for (int a = t; a < N_ATOMS; a += 256) {
      int s = sp_idx[a];
      atom_order[atomicAdd(&cur[s], 1)] = a;
    }
    if (t < N_SPECIES) {
      const int c = cnt[t], base = off[t], g0 = gb[t];
      const int ng = (c + GRP - 1) / GRP;
      for (int j = 0; j < ng; ++j) {
        grp_sp[g0 + j]   = t;
        grp_base[g0 + j] = base + j * GRP;
        grp_cnt[g0 + j]  = min(GRP, c - j * GRP);
      }
    }
    return;
  }
  const int NV = (N_SPECIES * HID * IN_F) / 4;  // float4 count per matrix
  const int nsplit = (gridDim.x - 1) * 256;
  for (int v = (blockIdx.x - 1) * 256 + t; v < 2 * NV; v += nsplit) {
    const float4* src; unsigned short* dh; unsigned short* dl; int j;
    if (v < NV) { src = (const float4*)W1; dh = w1h; dl = w1l; j = v; }
    else        { src = (const float4*)W2; dh = w2h; dl = w2l; j = v - NV; }
    float4 f = src[j];
    float vv[4] = {f.x, f.y, f.z, f.w};
    ushort4 h, l;
    HL s0 = split2(vv[0]); h.x = (unsigned short)s0.h; l.x = (unsigned short)s0.l;
    HL s1 = split2(vv[1]); h.y = (unsigned short)s1.h; l.y = (unsigned short)s1.l;
    HL s2 = split2(vv[2]); h.z = (unsigned short)s2.h; l.z = (unsigned short)s2.l;
    HL s3 = split2(vv[3]); h.w = (unsigned short)s3.h; l.w = (unsigned short)s3.l;
    ((ushort4*)dh)[j] = h;
    ((ushort4*)dl)[j] = l;
  }
}

// ---------- kernel 2: fused 2-layer MLP, 1 block = 8 waves = 8 atoms ----------
// LDS: dbuf x (w1 hi+lo 16KB + w2 hi+lo 16KB) = 64 KB + 8x4KB lx = 96 KB -> 1 blk/CU.
// Weight rows XOR-swizzled WITHIN cache lines (involution on source, linear LDS
// dest, same XOR on reads) -> coalesced staging + conflict-free ds_read_b128.
__global__ __launch_bounds__(512, 2) void mlp_kernel(
    const float* __restrict__ feat,
    const float* __restrict__ b1g, const float* __restrict__ b2g,
    const unsigned short* __restrict__ w1h, const unsigned short* __restrict__ w1l,
    const unsigned short* __restrict__ w2h, const unsigned short* __restrict__ w2l,
    const int* __restrict__ atom_order, const int* __restrict__ grp_sp,
    const int* __restrict__ grp_base, const int* __restrict__ grp_cnt,
    const int* __restrict__ n_groups,
    float* __restrict__ out) {
  // XCD-chunked swizzle (bijective over 576 = 8*72): XCD k handles contiguous
  // group ids [72k, 72k+72) -> same-species blocks share one L2.
  const int bid = blockIdx.x;
  const int g = (bid & 7) * (MAX_GROUPS / 8) + (bid >> 3);
  if (g >= *n_groups) return;
  const int s = grp_sp[g];
  const int abase = grp_base[g];
  const int cnt = grp_cnt[g];
  const int tid = threadIdx.x;
  const int wave = tid >> 6, lane = tid & 63;
  const int q = lane >> 4, r = lane & 15;

  __shared__ short lw1[2][2][32 * IN_F];    // [buf][hi/lo][row h_local(32) x i(128)]
  __shared__ short lw2[2][2][OUT_F * 32];   // [buf][hi/lo][row o(128) x h_local(32)]
  __shared__ float lx[8][N_NEIGH * 32];     // per-wave [n(32) x h_local(32)], swizzled

  const bool active = (wave < cnt);
  int atom = 0;

  // ---- staging: wave w stages half (w&1) of plane (w>>1); 4KB = 4 x 1KB instrs.
  // LDS dest linear; source pre-applies the within-row XOR involution.
  const int plane = wave >> 1, half = wave & 1;
  const bool isw1 = (plane < 2);
  const unsigned short* pl = (plane == 0) ? w1h : (plane == 1) ? w1l
                           : (plane == 2) ? w2h : w2l;
  const char* gplane = (const char*)pl + (long)s * (HID * IN_F) * 2;  // 64 KB/species
  const int hcstride = isw1 ? (32 * IN_F * 2) : (32 * 2);
  int srcoff[4], dstoff[4];
#pragma unroll
  for (int it = 0; it < 4; ++it) {
    const int b = half * 4096 + it * 1024 + lane * 16;
    if (isw1) {
      const int row = b >> 8;                       // 256 B rows (h_local)
      srcoff[it] = row * (IN_F * 2) + ((b & 255) ^ ((row & 7) << 4));
    } else {
      const int o = b >> 6;                         // 64 B rows (o)
      srcoff[it] = o * (HID * 2) + ((b & 63) ^ (((o >> 1) & 3) << 4));
    }
    dstoff[it] = b;
  }
  char* lplane0 = isw1 ? (char*)lw1[0][plane] : (char*)lw2[0][plane - 2];

  auto STAGE = [&](int buf, int hc) {
    const char* base = gplane + hc * hcstride;
    char* lp = lplane0 + buf * 16384;
#pragma unroll
    for (int it = 0; it < 4; ++it) {
      __builtin_amdgcn_global_load_lds(
          (const __attribute__((address_space(1))) unsigned int*)(base + srcoff[it]),
          (__attribute__((address_space(3))) unsigned int*)(lp + dstoff[it]),
          16, 0, 0);
    }
  };

  STAGE(0, 0);  // kick chunk 0 before the per-atom prologue

  // Feature A-fragments (registers, whole kernel): rows 16*nt + r, k = 32*ks + 8*q + j
  short8 fh[2][4], fl[2][4];
  if (active) {
    atom = atom_order[abase + wave];
    const float* fb = feat + (long)atom * (N_NEIGH * IN_F);
#pragma unroll
    for (int nt = 0; nt < 2; ++nt)
#pragma unroll
      for (int ks = 0; ks < 4; ++ks) {
        const float* p = fb + (16 * nt + r) * IN_F + 32 * ks + 8 * q;
        float4 v0 = *(const float4*)p;
        float4 v1 = *(const float4*)(p + 4);
        float vv[8] = {v0.x, v0.y, v0.z, v0.w, v1.x, v1.y, v1.z, v1.w};
        short8 h8, l8;
#pragma unroll
        for (int j = 0; j < 8; ++j) {
          HL hl = split2(vv[j]);
          h8[j] = hl.h;
          l8[j] = hl.l;
        }
        fh[nt][ks] = h8;
        fl[nt][ks] = l8;
      }
  }

  float b2v[8];
#pragma unroll
  for (int ot = 0; ot < 8; ++ot) b2v[ot] = b2g[s * OUT_F + 16 * ot + r];

  f32x4 oacc[2][8] = {};
  char* lxw = (char*)lx[wave];
  const int swz1 = (r & 7) << 4;          // w1 read XOR (row&7 == r&7, ht-indep)
  const int swz2 = ((r >> 1) & 3) << 4;   // w2 read XOR ((o>>1)&3, ot-indep)

  asm volatile("s_waitcnt vmcnt(0)" ::: "memory");
  __syncthreads();

  for (int hc = 0; hc < 8; ++hc) {
    const int buf = hc & 1;
    if (hc < 7) STAGE(buf ^ 1, hc + 1);  // prefetch next under this chunk's compute

    if (active) {
      // ---- layer 1: x[32 x 32] = feat(32x128) @ W1chunk^T, 3-term hi/lo
      f32x4 xacc[2][2] = {};
      const char* L1h = (const char*)lw1[buf][0];
      const char* L1l = (const char*)lw1[buf][1];
#pragma unroll
      for (int ks = 0; ks < 4; ++ks) {
        const int koff = 64 * ks + 16 * q;
#pragma unroll
        for (int ht = 0; ht < 2; ++ht) {
          const int byte = (16 * ht + r) * 256 + (koff ^ swz1);
          short8 bh = *(const short8*)(L1h + byte);
          short8 bl = *(const short8*)(L1l + byte);
#pragma unroll
          for (int nt = 0; nt < 2; ++nt) {
            xacc[nt][ht] = __builtin_amdgcn_mfma_f32_16x16x32_bf16(fh[nt][ks], bh, xacc[nt][ht], 0, 0, 0);
            xacc[nt][ht] = __builtin_amdgcn_mfma_f32_16x16x32_bf16(fh[nt][ks], bl, xacc[nt][ht], 0, 0, 0);
            xacc[nt][ht] = __builtin_amdgcn_mfma_f32_16x16x32_bf16(fl[nt][ks], bh, xacc[nt][ht], 0, 0, 0);
          }
        }
      }
      // ---- bias + SiLU, write per-wave x tile (fp32, swizzled)
#pragma unroll
      for (int ht = 0; ht < 2; ++ht) {
        const float b1v = b1g[s * HID + hc * 32 + 16 * ht + r];
#pragma unroll
        for (int nt = 0; nt < 2; ++nt)
#pragma unroll
          for (int i = 0; i < 4; ++i) {
            const int n = 16 * nt + 4 * q + i;
            float v = xacc[nt][ht][i] + b1v;
            v = v * __builtin_amdgcn_rcpf(1.0f + __expf(-v));
            int byte = (n << 7) + ((r + 16 * ht) << 2);
            byte ^= (n & 7) << 4;
            *(float*)(lxw + byte) = v;
          }
      }
      // ---- read back as layer-2 A-frags (row n = 16*nt + r, k = 8*q + j)
      short8 ah[2], al[2];
#pragma unroll
      for (int nt = 0; nt < 2; ++nt) {
        const int n = 16 * nt + r;
        const int base_b = (n << 7) + (q << 5);
        const int swz = (n & 7) << 4;
        float4 v0 = *(const float4*)(lxw + (base_b ^ swz));
        float4 v1 = *(const float4*)(lxw + ((base_b + 16) ^ swz));
        float vv[8] = {v0.x, v0.y, v0.z, v0.w, v1.x, v1.y, v1.z, v1.w};
        short8 h8, l8;
#pragma unroll
        for (int j = 0; j < 8; ++j) {
          HL hl = split2(vv[j]);
          h8[j] = hl.h;
          l8[j] = hl.l;
        }
        ah[nt] = h8;
        al[nt] = l8;
      }
      // ---- layer 2 partial: out += silu_x_chunk @ W2chunk^T
      const char* L2h = (const char*)lw2[buf][0];
      const char* L2l = (const char*)lw2[buf][1];
#pragma unroll
      for (int ot = 0; ot < 8; ++ot) {
        const int byte = (16 * ot + r) * 64 + ((16 * q) ^ swz2);
        short8 bh = *(const short8*)(L2h + byte);
        short8 bl = *(const short8*)(L2l + byte);
#pragma unroll
        for (int nt = 0; nt < 2; ++nt) {
          oacc[nt][ot] = __builtin_amdgcn_mfma_f32_16x16x32_bf16(ah[nt], bh, oacc[nt][ot], 0, 0, 0);
          oacc[nt][ot] = __builtin_amdgcn_mfma_f32_16x16x32_bf16(ah[nt], bl, oacc[nt][ot], 0, 0, 0);
          oacc[nt][ot] = __builtin_amdgcn_mfma_f32_16x16x32_bf16(al[nt], bh, oacc[nt][ot], 0, 0, 0);
        }
      }
    }
    // wait only this wave's own prefetch loads (issued one compute-phase ago)
    asm volatile("s_waitcnt vmcnt(0)" ::: "memory");
    __syncthreads();
  }

  if (active) {
    float* ob = out + (long)atom * (N_NEIGH * OUT_F);
#pragma unroll
    for (int nt = 0; nt < 2; ++nt)
#pragma unroll
      for (int ot = 0; ot < 8; ++ot)
#pragma unroll
        for (int i = 0; i < 4; ++i) {
          ob[(16 * nt + 4 * q + i) * OUT_F + 16 * ot + r] = oacc[nt][ot][i] + b2v[ot];
        }
  }
}

extern "C" void kernel_launch(void* const* d_in, const int* in_sizes, int n_in,
                              void* d_out, int out_size, void* d_ws, size_t ws_size,
                              hipStream_t stream) {
  const float* feat = (const float*)d_in[0];
  const int* sp     = (const int*)d_in[1];
  const float* W1   = (const float*)d_in[2];
  const float* b1   = (const float*)d_in[3];
  const float* W2   = (const float*)d_in[4];
  const float* b2   = (const float*)d_in[5];
  float* out = (float*)d_out;

  char* ws = (char*)d_ws;
  unsigned short* w1h = (unsigned short*)(ws + 0);
  unsigned short* w1l = (unsigned short*)(ws + 4194304);
  unsigned short* w2h = (unsigned short*)(ws + 8388608);
  unsigned short* w2l = (unsigned short*)(ws + 12582912);
  int* atom_order = (int*)(ws + 16777216);
  int* grp_sp     = (int*)(ws + 16777216 + 16384);
  int* grp_base   = (int*)(ws + 16777216 + 16384 + 4352);
  int* grp_cnt    = (int*)(ws + 16777216 + 16384 + 8704);
  int* n_groups   = (int*)(ws + 16777216 + 16384 + 13056);

  hipLaunchKernelGGL(prep_kernel, dim3(1025), dim3(256), 0, stream,
                     W1, W2, sp, w1h, w1l, w2h, w2l,
                     atom_order, grp_sp, grp_base, grp_cnt, n_groups);
  hipLaunchKernelGGL(mlp_kernel, dim3(MAX_GROUPS), dim3(512), 0, stream,
                     feat, b1, b2, w1h, w1l, w2h, w2l,
                     atom_order, grp_sp, grp_base, grp_cnt, n_groups, out);
}

// Round 6
// 192.173 us; speedup vs baseline: 1.0706x; 1.0706x over previous
//
#include <hip/hip_runtime.h>

typedef __attribute__((ext_vector_type(8))) short short8;
typedef __attribute__((ext_vector_type(4))) float f32x4;

#define N_ATOMS 4096
#define N_NEIGH 32
#define IN_F 128
#define HID 256
#define OUT_F 128
#define N_SPECIES 64
#define GRP 8
#define MAX_GROUPS 576  // sum ceil(c_s/8) <= 512+56; padded to 8*72 for swizzle

// RNE round to bf16 (for weights: 2-term split keeps only wh, so use RNE to
// halve the quantization error vs truncation).
__device__ __forceinline__ unsigned short f2bf(float f) {
  unsigned u = __float_as_uint(f);
  u += 0x7FFF + ((u >> 16) & 1);
  return (unsigned short)(u >> 16);
}
// Truncation hi/lo split for activations (hi exact chop, lo exact residual).
struct HL { short h, l; };
__device__ __forceinline__ HL split2(float v) {
  unsigned u = __float_as_uint(v);
  float lo = v - __uint_as_float(u & 0xFFFF0000u);
  HL o;
  o.h = (short)(u >> 16);
  o.l = (short)(__float_as_uint(lo) >> 16);
  return o;
}

// ---------- kernel 1: (block 0) counting sort | (blocks 1..) W -> bf16 RNE ----------
__global__ __launch_bounds__(256) void prep_kernel(
    const float* __restrict__ W1, const float* __restrict__ W2,
    const int* __restrict__ sp_idx,
    unsigned short* __restrict__ w1h, unsigned short* __restrict__ w2h,
    int* __restrict__ atom_order, int* __restrict__ grp_sp,
    int* __restrict__ grp_base, int* __restrict__ grp_cnt,
    int* __restrict__ n_groups) {
  const int t = threadIdx.x;
  if (blockIdx.x == 0) {
    __shared__ int cnt[N_SPECIES], off[N_SPECIES], cur[N_SPECIES], gb[N_SPECIES];
    if (t < N_SPECIES) cnt[t] = 0;
    __syncthreads();
    for (int a = t; a < N_ATOMS; a += 256) atomicAdd(&cnt[sp_idx[a]], 1);
    __syncthreads();
    if (t == 0) {
      int o = 0, g = 0;
      for (int s = 0; s < N_SPECIES; ++s) {
        off[s] = o; cur[s] = o; gb[s] = g;
        o += cnt[s];
        g += (cnt[s] + GRP - 1) / GRP;
      }
      *n_groups = g;
    }
    __syncthreads();
    for (int a = t; a < N_ATOMS; a += 256) {
      int s = sp_idx[a];
      atom_order[atomicAdd(&cur[s], 1)] = a;
    }
    if (t < N_SPECIES) {
      const int c = cnt[t], base = off[t], g0 = gb[t];
      const int ng = (c + GRP - 1) / GRP;
      for (int j = 0; j < ng; ++j) {
        grp_sp[g0 + j]   = t;
        grp_base[g0 + j] = base + j * GRP;
        grp_cnt[g0 + j]  = min(GRP, c - j * GRP);
      }
    }
    return;
  }
  const int NV = (N_SPECIES * HID * IN_F) / 4;  // float4 count per matrix
  const int nsplit = (gridDim.x - 1) * 256;
  for (int v = (blockIdx.x - 1) * 256 + t; v < 2 * NV; v += nsplit) {
    const float4* src; unsigned short* dh; int j;
    if (v < NV) { src = (const float4*)W1; dh = w1h; j = v; }
    else        { src = (const float4*)W2; dh = w2h; j = v - NV; }
    float4 f = src[j];
    ushort4 h;
    h.x = f2bf(f.x); h.y = f2bf(f.y); h.z = f2bf(f.z); h.w = f2bf(f.w);
    ((ushort4*)dh)[j] = h;
  }
}

// ---------- kernel 2: fused 2-layer MLP, weights FULLY LDS-RESIDENT ----------
// 1 block = 8 waves = 8 atoms (one species). LDS 160 KB:
//   W1h 64 KB ([256 h][128 i], rows XOR-swizzled ^(h&7)<<4)
//   W2h 64 KB ([128 o][256 k], rows XOR-swizzled ^(o&7)<<4)
//   lx  8 x 4 KB per-wave x-transpose tile (bit-6 flip swizzle)
// Stage once -> ONE barrier -> zero barriers / zero vmcnt in the main loop:
// waves free-run, so MFMA/VALU/LDS co-schedule across the 2 waves/SIMD.
__global__ __launch_bounds__(512, 2) void mlp_kernel(
    const float* __restrict__ feat,
    const float* __restrict__ b1g, const float* __restrict__ b2g,
    const unsigned short* __restrict__ w1h, const unsigned short* __restrict__ w2h,
    const int* __restrict__ atom_order, const int* __restrict__ grp_sp,
    const int* __restrict__ grp_base, const int* __restrict__ grp_cnt,
    const int* __restrict__ n_groups,
    float* __restrict__ out) {
  extern __shared__ char smem[];
  char* LW1 = smem;            // 64 KB
  char* LW2 = smem + 65536;    // 64 KB
  // lx per-wave at smem + 131072 + wave*4096

  const int bid = blockIdx.x;
  const int g = (bid & 7) * (MAX_GROUPS / 8) + (bid >> 3);  // XCD-chunked, bijective
  if (g >= *n_groups) return;
  const int s = grp_sp[g];
  const int abase = grp_base[g];
  const int cnt = grp_cnt[g];
  const int tid = threadIdx.x;
  const int wave = tid >> 6, lane = tid & 63;
  const int q = lane >> 4, r = lane & 15;
  const bool active = (wave < cnt);

  // ---- stage both weight planes once (coalesced 16B, source pre-XORed rule-21)
  {
    const char* gw1 = (const char*)w1h + (long)s * (HID * IN_F * 2);
    const char* gw2 = (const char*)w2h + (long)s * (OUT_F * HID * 2);
#pragma unroll
    for (int it = 0; it < 8; ++it) {   // W1h: 64 KB
      const int d = it * 8192 + tid * 16;
      const int h = d >> 8, w = d & 255;               // 256 B rows
      const int src = h * (IN_F * 2) + (w ^ ((h & 7) << 4));
      __builtin_amdgcn_global_load_lds(
          (const __attribute__((address_space(1))) unsigned int*)(gw1 + src),
          (__attribute__((address_space(3))) unsigned int*)(LW1 + d), 16, 0, 0);
    }
#pragma unroll
    for (int it = 0; it < 8; ++it) {   // W2h: 64 KB
      const int d = it * 8192 + tid * 16;
      const int o = d >> 9, w = d & 511;               // 512 B rows
      const int src = o * (HID * 2) + (w ^ ((o & 7) << 4));
      __builtin_amdgcn_global_load_lds(
          (const __attribute__((address_space(1))) unsigned int*)(gw2 + src),
          (__attribute__((address_space(3))) unsigned int*)(LW2 + d), 16, 0, 0);
    }
  }

  // ---- features into registers while staging is in flight
  short8 fh[2][4], fl[2][4];
  int atom = 0;
  if (active) {
    atom = atom_order[abase + wave];
    const float* fb = feat + (long)atom * (N_NEIGH * IN_F);
#pragma unroll
    for (int nt = 0; nt < 2; ++nt)
#pragma unroll
      for (int ks = 0; ks < 4; ++ks) {
        const float* p = fb + (16 * nt + r) * IN_F + 32 * ks + 8 * q;
        float4 v0 = *(const float4*)p;
        float4 v1 = *(const float4*)(p + 4);
        float vv[8] = {v0.x, v0.y, v0.z, v0.w, v1.x, v1.y, v1.z, v1.w};
        short8 h8, l8;
#pragma unroll
        for (int j = 0; j < 8; ++j) {
          HL hl = split2(vv[j]);
          h8[j] = hl.h;
          l8[j] = hl.l;
        }
        fh[nt][ks] = h8;
        fl[nt][ks] = l8;
      }
  }

  asm volatile("s_waitcnt vmcnt(0)" ::: "memory");
  __syncthreads();  // the ONLY barrier

  if (!active) return;

  f32x4 oacc[2][8] = {};
  char* lxw = smem + 131072 + wave * 4096;  // [32 n][32 h] fp32, bit6-flip swizzle
  const int swz = (r & 7) << 4;
  const float* b1s = b1g + s * HID;

  for (int hc = 0; hc < 8; ++hc) {
    // ---- layer 1: x[32 x 32] = feat @ W1h-chunk^T  (2-term: fh*wh + fl*wh)
    f32x4 xacc[2][2] = {};
#pragma unroll
    for (int ks = 0; ks < 4; ++ks) {
      const int ib = ((32 * ks + 8 * q) * 2) ^ swz;
#pragma unroll
      for (int ht = 0; ht < 2; ++ht) {
        const int row = 32 * hc + 16 * ht + r;         // row&7 == r&7
        short8 bh = *(const short8*)(LW1 + row * 256 + ib);
        xacc[0][ht] = __builtin_amdgcn_mfma_f32_16x16x32_bf16(fh[0][ks], bh, xacc[0][ht], 0, 0, 0);
        xacc[1][ht] = __builtin_amdgcn_mfma_f32_16x16x32_bf16(fh[1][ks], bh, xacc[1][ht], 0, 0, 0);
        xacc[0][ht] = __builtin_amdgcn_mfma_f32_16x16x32_bf16(fl[0][ks], bh, xacc[0][ht], 0, 0, 0);
        xacc[1][ht] = __builtin_amdgcn_mfma_f32_16x16x32_bf16(fl[1][ks], bh, xacc[1][ht], 0, 0, 0);
      }
    }
    // ---- bias + SiLU -> per-wave lx tile (write: n=16nt+4q+i, h=16ht+r)
#pragma unroll
    for (int ht = 0; ht < 2; ++ht) {
      const float b1v = b1s[hc * 32 + 16 * ht + r];
#pragma unroll
      for (int nt = 0; nt < 2; ++nt)
#pragma unroll
        for (int i = 0; i < 4; ++i) {
          const int n = 16 * nt + 4 * q + i;
          float v = xacc[nt][ht][i] + b1v;
          v = v * __builtin_amdgcn_rcpf(1.0f + __expf(-v));
          const int byte = n * 128 + (((16 * ht + r) * 4) ^ ((q & 1) << 6));
          *(float*)(lxw + byte) = v;
        }
    }
    // ---- read back as layer-2 A-frags (row n=16nt+r, k=8q+j) + split
    short8 ah[2], al[2];
#pragma unroll
    for (int nt = 0; nt < 2; ++nt) {
      const int n = 16 * nt + r;
      const int base_b = n * 128 + ((32 * q) ^ (((r >> 2) & 1) << 6));
      float4 v0 = *(const float4*)(lxw + base_b);
      float4 v1 = *(const float4*)(lxw + base_b + 16);
      float vv[8] = {v0.x, v0.y, v0.z, v0.w, v1.x, v1.y, v1.z, v1.w};
      short8 h8, l8;
#pragma unroll
      for (int j = 0; j < 8; ++j) {
        HL hl = split2(vv[j]);
        h8[j] = hl.h;
        l8[j] = hl.l;
      }
      ah[nt] = h8;
      al[nt] = l8;
    }
    // ---- layer 2 partial: out += x-chunk @ W2h-chunk^T (2-term: ah*wh + al*wh)
    const int kb = ((32 * hc + 8 * q) * 2) ^ swz;
#pragma unroll
    for (int ot = 0; ot < 8; ++ot) {
      const int row = 16 * ot + r;                      // row&7 == r&7
      short8 bw = *(const short8*)(LW2 + row * 512 + kb);
      oacc[0][ot] = __builtin_amdgcn_mfma_f32_16x16x32_bf16(ah[0], bw, oacc[0][ot], 0, 0, 0);
      oacc[1][ot] = __builtin_amdgcn_mfma_f32_16x16x32_bf16(ah[1], bw, oacc[1][ot], 0, 0, 0);
      oacc[0][ot] = __builtin_amdgcn_mfma_f32_16x16x32_bf16(al[0], bw, oacc[0][ot], 0, 0, 0);
      oacc[1][ot] = __builtin_amdgcn_mfma_f32_16x16x32_bf16(al[1], bw, oacc[1][ot], 0, 0, 0);
    }
  }

  // ---- epilogue: bias2 + store
  float* ob = out + (long)atom * (N_NEIGH * OUT_F);
#pragma unroll
  for (int ot = 0; ot < 8; ++ot) {
    const float b2v = b2g[s * OUT_F + 16 * ot + r];
#pragma unroll
    for (int nt = 0; nt < 2; ++nt)
#pragma unroll
      for (int i = 0; i < 4; ++i) {
        ob[(16 * nt + 4 * q + i) * OUT_F + 16 * ot + r] = oacc[nt][ot][i] + b2v;
      }
  }
}

extern "C" void kernel_launch(void* const* d_in, const int* in_sizes, int n_in,
                              void* d_out, int out_size, void* d_ws, size_t ws_size,
                              hipStream_t stream) {
  const float* feat = (const float*)d_in[0];
  const int* sp     = (const int*)d_in[1];
  const float* W1   = (const float*)d_in[2];
  const float* b1   = (const float*)d_in[3];
  const float* W2   = (const float*)d_in[4];
  const float* b2   = (const float*)d_in[5];
  float* out = (float*)d_out;

  char* ws = (char*)d_ws;
  unsigned short* w1h = (unsigned short*)(ws + 0);
  unsigned short* w2h = (unsigned short*)(ws + 4194304);
  int* atom_order = (int*)(ws + 8388608);
  int* grp_sp     = (int*)(ws + 8388608 + 16384);
  int* grp_base   = (int*)(ws + 8388608 + 16384 + 4352);
  int* grp_cnt    = (int*)(ws + 8388608 + 16384 + 8704);
  int* n_groups   = (int*)(ws + 8388608 + 16384 + 13056);

  hipFuncSetAttribute((const void*)mlp_kernel,
                      hipFuncAttributeMaxDynamicSharedMemorySize, 163840);

  hipLaunchKernelGGL(prep_kernel, dim3(1025), dim3(256), 0, stream,
                     W1, W2, sp, w1h, w2h,
                     atom_order, grp_sp, grp_base, grp_cnt, n_groups);
  hipLaunchKernelGGL(mlp_kernel, dim3(MAX_GROUPS), dim3(512), 163840, stream,
                     feat, b1, b2, w1h, w2h,
                     atom_order, grp_sp, grp_base, grp_cnt, n_groups, out);
}